// Round 4
// baseline (553.528 us; speedup 1.0000x reference)
//
#include <hip/hip_runtime.h>
#include <hip/hip_bf16.h>

#define NTOK 512
#define HDIM 2880
#define NGU  5760
#define NEXP 16
#define KSTEPS 90   // 2880 / 32
#define MT 160      // m-tile rows (covers n_e up to 160 in one tile)
#define MFR 10      // MT/16 m-fragments

typedef float  f32x4  __attribute__((ext_vector_type(4)));
typedef float  f32x2  __attribute__((ext_vector_type(2)));
typedef short  bf16x8 __attribute__((ext_vector_type(8)));

__device__ __forceinline__ unsigned short f2bf(float f) {
  union { float f; unsigned u; } a; a.f = f;
  unsigned r = a.u + 0x7FFFu + ((a.u >> 16) & 1u);   // RNE truncate to bf16
  return (unsigned short)(r >> 16);
}

// Barrier that does NOT drain vmcnt: LDS-only wait + raw s_barrier.
// B-register prefetch loads stay in flight across it (the whole point).
// lgkmcnt(0) drains this wave's ds_writes AND ds_reads (covers RAW+WAR on
// both LDS buffers); the trailing empty asm is a compiler fence —
// s_barrier is IntrNoMem in LLVM, so without it memory ops could be
// compile-time hoisted across the barrier.
__device__ __forceinline__ void lds_barrier() {
  asm volatile("s_waitcnt lgkmcnt(0)" ::: "memory");
  __builtin_amdgcn_s_barrier();
  asm volatile("" ::: "memory");
}

// ---------------- control kernels ----------------

__global__ void k_zero(int* counts) {
  if (threadIdx.x < NEXP) counts[threadIdx.x] = 0;
}

__global__ __launch_bounds__(256) void k_router(
    const float* __restrict__ x, const float* __restrict__ rw,
    const float* __restrict__ rb, int* __restrict__ counts,
    int* __restrict__ top_e, float* __restrict__ top_w)
{
  const int t = blockIdx.x;
  const int tid = threadIdx.x;
  __shared__ float red[256][17];
  float acc[NEXP];
#pragma unroll
  for (int e = 0; e < NEXP; ++e) acc[e] = 0.f;
  const float* xr = x + (size_t)t * HDIM;
  for (int h = tid; h < HDIM; h += 256) {
    float xv = xr[h];
    const f32x4* wr = (const f32x4*)(rw + (size_t)h * NEXP);
#pragma unroll
    for (int q = 0; q < 4; ++q) {
      f32x4 w = wr[q];
#pragma unroll
      for (int j = 0; j < 4; ++j) acc[q*4+j] += xv * w[j];
    }
  }
#pragma unroll
  for (int e = 0; e < NEXP; ++e) red[tid][e] = acc[e];
  __syncthreads();
  for (int s = 128; s > 0; s >>= 1) {
    if (tid < s) {
#pragma unroll
      for (int e = 0; e < NEXP; ++e) red[tid][e] += red[tid + s][e];
    }
    __syncthreads();
  }
  if (tid == 0) {
    float v[NEXP];
#pragma unroll
    for (int e = 0; e < NEXP; ++e) v[e] = red[0][e] + rb[e];
    int mask = 0; float tv[4]; int ti[4];
    for (int k = 0; k < 4; ++k) {
      float best = -3.4e38f; int bi = 0;
      for (int e = 0; e < NEXP; ++e)
        if (!((mask >> e) & 1) && v[e] > best) { best = v[e]; bi = e; }
      mask |= 1 << bi; tv[k] = best; ti[k] = bi;
    }
    float s = 0.f, ex[4];
    for (int k = 0; k < 4; ++k) { ex[k] = __expf(tv[k] - tv[0]); s += ex[k]; }
    float inv = 1.f / s;
    for (int k = 0; k < 4; ++k) {
      top_e[t*4+k] = ti[k];
      top_w[t*4+k] = ex[k] * inv;
      atomicAdd(&counts[ti[k]], 1);
    }
  }
}

__global__ void k_scan(const int* __restrict__ counts, int* __restrict__ seg) {
  int s = 0;
  for (int e = 0; e < NEXP; ++e) { seg[e] = s; s += counts[e]; }
  seg[NEXP] = s;
}

// one wave per expert; deterministic, token-ordered compaction.
// NOTE: no tail padding — all consumers guard reads with (m0+r < n_e).
__global__ __launch_bounds__(64) void k_fill(
    const int* __restrict__ top_e, const float* __restrict__ top_w,
    const int* __restrict__ seg, int* __restrict__ pair_tok, float* __restrict__ pair_w)
{
  const int e = blockIdx.x;
  const int lane = threadIdx.x;
  int base = seg[e];
  for (int t0 = 0; t0 < NTOK; t0 += 64) {
    int t = t0 + lane;
    int my = -1;
#pragma unroll
    for (int k = 0; k < 4; ++k) if (top_e[t*4+k] == e) my = k;
    unsigned long long m = __ballot(my >= 0);
    if (my >= 0) {
      int pre = __popcll(m & ((1ull << lane) - 1ull));
      pair_tok[base + pre] = t;
      pair_w[base + pre] = top_w[t*4+my];
    }
    base += (int)__popcll(m);
  }
}

// x (f32) -> xb (bf16), once
__global__ __launch_bounds__(256) void k_xbf16(
    const float* __restrict__ x, unsigned short* __restrict__ xb)
{
  int i = (blockIdx.x * 256 + threadIdx.x) * 8;
  f32x4 a = *(const f32x4*)(x + i);
  f32x4 b = *(const f32x4*)(x + i + 4);
  bf16x8 o;
#pragma unroll
  for (int j = 0; j < 4; ++j) { o[j] = (short)f2bf(a[j]); o[4+j] = (short)f2bf(b[j]); }
  *(bf16x8*)(xb + i) = o;
}

// out[t][h] = sum_k w_k * down_b[e_k][h]  (down bias, score-weighted)
__global__ __launch_bounds__(256) void k_outinit(
    const int* __restrict__ top_e, const float* __restrict__ top_w,
    const float* __restrict__ db, float* __restrict__ out)
{
  const int t = blockIdx.x;
  const int tid = threadIdx.x;
  const int e0 = top_e[t*4+0], e1 = top_e[t*4+1], e2 = top_e[t*4+2], e3 = top_e[t*4+3];
  const float w0 = top_w[t*4+0], w1 = top_w[t*4+1], w2 = top_w[t*4+2], w3 = top_w[t*4+3];
  const float* b0 = db + (size_t)e0 * HDIM;
  const float* b1 = db + (size_t)e1 * HDIM;
  const float* b2 = db + (size_t)e2 * HDIM;
  const float* b3 = db + (size_t)e3 * HDIM;
  for (int h = tid; h < HDIM; h += 256)
    out[(size_t)t*HDIM + h] = w0*b0[h] + w1*b1[h] + w2*b2[h] + w3*b3[h];
}

// ---------------- gate_up + activation ----------------
// block = MT token-rows x 64 features; 4 waves, wave w owns 16 features.
// A (xb rows, gathered) -> LDS, double buffered (ds_write + lgkm-only barrier).
// B (gate_up_w) -> regs, prefetched at distance 2, loads live across barriers.
__global__ __launch_bounds__(256, 3) void k_gateup(
    const unsigned short* __restrict__ xb, const float* __restrict__ gw,
    const float* __restrict__ gb, const int* __restrict__ seg,
    const int* __restrict__ pair_tok, const float* __restrict__ pair_w,
    unsigned short* __restrict__ act)
{
  const int e = blockIdx.z;
  const int segs = seg[e];
  const int n_e = seg[e+1] - segs;
  const int m0 = blockIdx.y * MT;
  if (m0 >= n_e) return;
  const int tid = threadIdx.x;
  const int lane = tid & 63;
  const int wid = tid >> 6;
  const int l15 = lane & 15, lg = lane >> 4;
  const int fc = blockIdx.x * 64 + wid * 16 + l15;   // feature pair index (0..2879)

  __shared__ unsigned short Alds[2][MT][40];

  const float* Bp = gw + (size_t)e * HDIM * NGU + 2*fc + (size_t)lg * 8 * NGU;

  // staging: task = row*2 + half; thread covers task=tid and task=tid+256
  const unsigned short* sp0 = nullptr;
  const unsigned short* sp1 = nullptr;
  const int r0 = tid >> 1, h0 = tid & 1;
  const int r1 = (tid + 256) >> 1, h1 = tid & 1;   // tid+256 parity == tid parity
  if (m0 + r0 < n_e) sp0 = xb + (size_t)pair_tok[segs + m0 + r0] * HDIM + h0*16;
  if (tid < 2*MT - 256 && m0 + r1 < n_e)
    sp1 = xb + (size_t)pair_tok[segs + m0 + r1] * HDIM + h1*16;

  f32x4 accg[MFR], accu[MFR];
  {
    f32x2 b = *(const f32x2*)(gb + (size_t)e * NGU + 2*fc);
#pragma unroll
    for (int m = 0; m < MFR; ++m)
#pragma unroll
      for (int r = 0; r < 4; ++r) { accg[m][r] = b[0]; accu[m][r] = b[1]; }
  }

  auto stage = [&](int ks, int b) {
    bf16x8 z = {0,0,0,0,0,0,0,0};
    bf16x8 v0 = z, v1 = z;
    if (sp0) { v0 = *(const bf16x8*)(sp0 + ks*32); v1 = *(const bf16x8*)(sp0 + ks*32 + 8); }
    *(bf16x8*)&Alds[b][r0][h0*16]     = v0;
    *(bf16x8*)&Alds[b][r0][h0*16 + 8] = v1;
    if (tid < 2*MT - 256) {
      bf16x8 w0 = z, w1 = z;
      if (sp1) { w0 = *(const bf16x8*)(sp1 + ks*32); w1 = *(const bf16x8*)(sp1 + ks*32 + 8); }
      *(bf16x8*)&Alds[b][r1][h1*16]     = w0;
      *(bf16x8*)&Alds[b][r1][h1*16 + 8] = w1;
    }
  };

  f32x2 bA[8], bB[8];
#pragma unroll
  for (int j = 0; j < 8; ++j) bA[j] = *(const f32x2*)(Bp + (size_t)j * NGU);
#pragma unroll
  for (int j = 0; j < 8; ++j) bB[j] = *(const f32x2*)(Bp + (size_t)(32 + j) * NGU);
  stage(0, 0);
  lds_barrier();

  for (int ks = 0; ks < KSTEPS; ks += 2) {
    // ---- sub-iter ks (A buf 0, B regs bA) ----
    stage(ks + 1, 1);
    bf16x8 bg, bu;
#pragma unroll
    for (int j = 0; j < 8; ++j) { bg[j] = (short)f2bf(bA[j][0]); bu[j] = (short)f2bf(bA[j][1]); }
    if (ks + 2 < KSTEPS) {
      const float* bp = Bp + (size_t)((ks+2)*32) * NGU;
#pragma unroll
      for (int j = 0; j < 8; ++j) bA[j] = *(const f32x2*)(bp + (size_t)j * NGU);
    }
#pragma unroll
    for (int m = 0; m < MFR; ++m) {
      bf16x8 a = *(const bf16x8*)&Alds[0][m*16 + l15][lg*8];
      accg[m] = __builtin_amdgcn_mfma_f32_16x16x32_bf16(a, bg, accg[m], 0, 0, 0);
      accu[m] = __builtin_amdgcn_mfma_f32_16x16x32_bf16(a, bu, accu[m], 0, 0, 0);
    }
    lds_barrier();
    // ---- sub-iter ks+1 (A buf 1, B regs bB) ----
    if (ks + 2 < KSTEPS) stage(ks + 2, 0);
#pragma unroll
    for (int j = 0; j < 8; ++j) { bg[j] = (short)f2bf(bB[j][0]); bu[j] = (short)f2bf(bB[j][1]); }
    if (ks + 3 < KSTEPS) {
      const float* bp = Bp + (size_t)((ks+3)*32) * NGU;
#pragma unroll
      for (int j = 0; j < 8; ++j) bB[j] = *(const f32x2*)(bp + (size_t)j * NGU);
    }
#pragma unroll
    for (int m = 0; m < MFR; ++m) {
      bf16x8 a = *(const bf16x8*)&Alds[1][m*16 + l15][lg*8];
      accg[m] = __builtin_amdgcn_mfma_f32_16x16x32_bf16(a, bg, accg[m], 0, 0, 0);
      accu[m] = __builtin_amdgcn_mfma_f32_16x16x32_bf16(a, bu, accu[m], 0, 0, 0);
    }
    lds_barrier();
  }

  // activation epilogue; fold router score into stored activation
#pragma unroll
  for (int m = 0; m < MFR; ++m) {
#pragma unroll
    for (int r = 0; r < 4; ++r) {
      int grow = m0 + m*16 + lg*4 + r;
      if (grow < n_e) {
        float g = accg[m][r], u = accu[m][r];
        g = fminf(g, 7.f);
        u = fminf(fmaxf(u, -7.f), 7.f);
        float glu = g / (1.f + __expf(-1.702f * g));
        float av = (u + 1.f) * glu * pair_w[segs + grow];
        act[(size_t)(segs + grow) * HDIM + fc] = f2bf(av);
      }
    }
  }
}

// ---------------- down projection ----------------
__global__ __launch_bounds__(256, 4) void k_down(
    const unsigned short* __restrict__ act, const float* __restrict__ dw,
    const int* __restrict__ seg, const int* __restrict__ pair_tok,
    float* __restrict__ out)
{
  const int e = blockIdx.z;
  const int segs = seg[e];
  const int n_e = seg[e+1] - segs;
  const int m0 = blockIdx.y * MT;
  if (m0 >= n_e) return;
  const int tid = threadIdx.x;
  const int lane = tid & 63;
  const int wid = tid >> 6;
  const int l15 = lane & 15, lg = lane >> 4;
  const int c = blockIdx.x * 64 + wid * 16 + l15;

  __shared__ unsigned short Alds[2][MT][40];

  const float* Bp = dw + (size_t)e * HDIM * HDIM + c + (size_t)lg * 8 * HDIM;

  const unsigned short* sp0 = nullptr;
  const unsigned short* sp1 = nullptr;
  const int r0 = tid >> 1, h0 = tid & 1;
  const int r1 = (tid + 256) >> 1, h1 = tid & 1;
  if (m0 + r0 < n_e) sp0 = act + (size_t)(segs + m0 + r0) * HDIM + h0*16;
  if (tid < 2*MT - 256 && m0 + r1 < n_e)
    sp1 = act + (size_t)(segs + m0 + r1) * HDIM + h1*16;

  f32x4 acc[MFR];
#pragma unroll
  for (int m = 0; m < MFR; ++m)
#pragma unroll
    for (int r = 0; r < 4; ++r) acc[m][r] = 0.f;

  auto stage = [&](int ks, int b) {
    bf16x8 z = {0,0,0,0,0,0,0,0};
    bf16x8 v0 = z, v1 = z;
    if (sp0) { v0 = *(const bf16x8*)(sp0 + ks*32); v1 = *(const bf16x8*)(sp0 + ks*32 + 8); }
    *(bf16x8*)&Alds[b][r0][h0*16]     = v0;
    *(bf16x8*)&Alds[b][r0][h0*16 + 8] = v1;
    if (tid < 2*MT - 256) {
      bf16x8 w0 = z, w1 = z;
      if (sp1) { w0 = *(const bf16x8*)(sp1 + ks*32); w1 = *(const bf16x8*)(sp1 + ks*32 + 8); }
      *(bf16x8*)&Alds[b][r1][h1*16]     = w0;
      *(bf16x8*)&Alds[b][r1][h1*16 + 8] = w1;
    }
  };

  float bA[8], bB[8];
#pragma unroll
  for (int j = 0; j < 8; ++j) bA[j] = Bp[(size_t)j * HDIM];
#pragma unroll
  for (int j = 0; j < 8; ++j) bB[j] = Bp[(size_t)(32 + j) * HDIM];
  stage(0, 0);
  lds_barrier();

  for (int ks = 0; ks < KSTEPS; ks += 2) {
    // ---- sub-iter ks (A buf 0, B regs bA) ----
    stage(ks + 1, 1);
    bf16x8 bfrag;
#pragma unroll
    for (int j = 0; j < 8; ++j) bfrag[j] = (short)f2bf(bA[j]);
    if (ks + 2 < KSTEPS) {
      const float* bp = Bp + (size_t)((ks+2)*32) * HDIM;
#pragma unroll
      for (int j = 0; j < 8; ++j) bA[j] = bp[(size_t)j * HDIM];
    }
#pragma unroll
    for (int m = 0; m < MFR; ++m) {
      bf16x8 a = *(const bf16x8*)&Alds[0][m*16 + l15][lg*8];
      acc[m] = __builtin_amdgcn_mfma_f32_16x16x32_bf16(a, bfrag, acc[m], 0, 0, 0);
    }
    lds_barrier();
    // ---- sub-iter ks+1 (A buf 1, B regs bB) ----
    if (ks + 2 < KSTEPS) stage(ks + 2, 0);
#pragma unroll
    for (int j = 0; j < 8; ++j) bfrag[j] = (short)f2bf(bB[j]);
    if (ks + 3 < KSTEPS) {
      const float* bp = Bp + (size_t)((ks+3)*32) * HDIM;
#pragma unroll
      for (int j = 0; j < 8; ++j) bB[j] = bp[(size_t)j * HDIM];
    }
#pragma unroll
    for (int m = 0; m < MFR; ++m) {
      bf16x8 a = *(const bf16x8*)&Alds[1][m*16 + l15][lg*8];
      acc[m] = __builtin_amdgcn_mfma_f32_16x16x32_bf16(a, bfrag, acc[m], 0, 0, 0);
    }
    lds_barrier();
  }

#pragma unroll
  for (int m = 0; m < MFR; ++m) {
#pragma unroll
    for (int r = 0; r < 4; ++r) {
      int grow = m0 + m*16 + lg*4 + r;
      if (grow < n_e) {
        int t = pair_tok[segs + grow];
        atomicAdd(out + (size_t)t * HDIM + c, acc[m][r]);
      }
    }
  }
}

// ---------------- launch ----------------

extern "C" void kernel_launch(void* const* d_in, const int* in_sizes, int n_in,
                              void* d_out, int out_size, void* d_ws, size_t ws_size,
                              hipStream_t stream) {
  const float* x  = (const float*)d_in[0];
  const float* rw = (const float*)d_in[1];
  const float* rb = (const float*)d_in[2];
  const float* gw = (const float*)d_in[3];
  const float* gb = (const float*)d_in[4];
  const float* dw = (const float*)d_in[5];
  const float* db = (const float*)d_in[6];
  float* out = (float*)d_out;

  char* w = (char*)d_ws;
  int*   counts   = (int*)(w);
  int*   seg      = (int*)(w + 64);
  int*   top_e    = (int*)(w + 1024);
  float* top_w    = (float*)(w + 1024 + 8192);
  int*   pair_tok = (int*)(w + 1024 + 16384);
  float* pair_w   = (float*)(w + 1024 + 24576);
  unsigned short* xb  = (unsigned short*)(w + (1 << 20));            // 512 x 2880 bf16 = 2.95 MB
  unsigned short* act = (unsigned short*)(w + (8 << 20));            // 2048 x 2880 bf16

  k_zero<<<1, 64, 0, stream>>>(counts);
  k_router<<<NTOK, 256, 0, stream>>>(x, rw, rb, counts, top_e, top_w);
  k_scan<<<1, 1, 0, stream>>>(counts, seg);
  k_fill<<<NEXP, 64, 0, stream>>>(top_e, top_w, seg, pair_tok, pair_w);
  k_xbf16<<<(NTOK*HDIM)/(256*8), 256, 0, stream>>>(x, xb);
  k_outinit<<<NTOK, 256, 0, stream>>>(top_e, top_w, db, out);

  dim3 gg(45, 2, NEXP);   // 45 feature tiles x {main, overflow} x experts
  k_gateup<<<gg, 256, 0, stream>>>(xb, gw, gb, seg, pair_tok, pair_w, act);

  dim3 gd(45, 2, NEXP);
  k_down<<<gd, 256, 0, stream>>>(act, dw, seg, pair_tok, out);
}

// Round 5
// 487.003 us; speedup vs baseline: 1.1366x; 1.1366x over previous
//
#include <hip/hip_runtime.h>
#include <hip/hip_bf16.h>

#define NTOK 512
#define HDIM 2880
#define NGU  5760
#define NEXP 16
#define KSTEPS 90   // 2880 / 32
#define MT 160      // m-tile rows (covers n_e up to 160 in one tile)
#define MFR 10      // MT/16 m-fragments

typedef float  f32x4  __attribute__((ext_vector_type(4)));
typedef float  f32x2  __attribute__((ext_vector_type(2)));
typedef short  bf16x8 __attribute__((ext_vector_type(8)));

__device__ __forceinline__ unsigned short f2bf(float f) {
  union { float f; unsigned u; } a; a.f = f;
  unsigned r = a.u + 0x7FFFu + ((a.u >> 16) & 1u);   // RNE truncate to bf16
  return (unsigned short)(r >> 16);
}

// Barrier that does NOT drain vmcnt: LDS-only wait + raw s_barrier.
// lgkmcnt(0) drains this wave's ds_writes AND ds_reads (RAW+WAR on both LDS
// buffers safe); trailing empty asm = compiler fence (s_barrier is IntrNoMem).
__device__ __forceinline__ void lds_barrier() {
  asm volatile("s_waitcnt lgkmcnt(0)" ::: "memory");
  __builtin_amdgcn_s_barrier();
  asm volatile("" ::: "memory");
}

// ---------------- control kernels ----------------

__global__ void k_zero(int* counts) {
  if (threadIdx.x < NEXP) counts[threadIdx.x] = 0;
}

__global__ __launch_bounds__(256) void k_router(
    const float* __restrict__ x, const float* __restrict__ rw,
    const float* __restrict__ rb, int* __restrict__ counts,
    int* __restrict__ top_e, float* __restrict__ top_w)
{
  const int t = blockIdx.x;
  const int tid = threadIdx.x;
  __shared__ float red[256][17];
  float acc[NEXP];
#pragma unroll
  for (int e = 0; e < NEXP; ++e) acc[e] = 0.f;
  const float* xr = x + (size_t)t * HDIM;
  for (int h = tid; h < HDIM; h += 256) {
    float xv = xr[h];
    const f32x4* wr = (const f32x4*)(rw + (size_t)h * NEXP);
#pragma unroll
    for (int q = 0; q < 4; ++q) {
      f32x4 w = wr[q];
#pragma unroll
      for (int j = 0; j < 4; ++j) acc[q*4+j] += xv * w[j];
    }
  }
#pragma unroll
  for (int e = 0; e < NEXP; ++e) red[tid][e] = acc[e];
  __syncthreads();
  for (int s = 128; s > 0; s >>= 1) {
    if (tid < s) {
#pragma unroll
      for (int e = 0; e < NEXP; ++e) red[tid][e] += red[tid + s][e];
    }
    __syncthreads();
  }
  if (tid == 0) {
    float v[NEXP];
#pragma unroll
    for (int e = 0; e < NEXP; ++e) v[e] = red[0][e] + rb[e];
    int mask = 0; float tv[4]; int ti[4];
    for (int k = 0; k < 4; ++k) {
      float best = -3.4e38f; int bi = 0;
      for (int e = 0; e < NEXP; ++e)
        if (!((mask >> e) & 1) && v[e] > best) { best = v[e]; bi = e; }
      mask |= 1 << bi; tv[k] = best; ti[k] = bi;
    }
    float s = 0.f, ex[4];
    for (int k = 0; k < 4; ++k) { ex[k] = __expf(tv[k] - tv[0]); s += ex[k]; }
    float inv = 1.f / s;
    for (int k = 0; k < 4; ++k) {
      top_e[t*4+k] = ti[k];
      top_w[t*4+k] = ex[k] * inv;
      atomicAdd(&counts[ti[k]], 1);
    }
  }
}

// one wave per expert; deterministic compaction; prefix-scan folded in.
__global__ __launch_bounds__(64) void k_fill(
    const int* __restrict__ top_e, const float* __restrict__ top_w,
    const int* __restrict__ counts, int* __restrict__ seg,
    int* __restrict__ pair_tok, float* __restrict__ pair_w)
{
  const int e = blockIdx.x;
  const int lane = threadIdx.x;
  int base = 0;
  for (int i = 0; i < e; ++i) base += counts[i];
  if (lane == 0) {
    seg[e] = base;
    if (e == NEXP - 1) seg[NEXP] = base + counts[e];
  }
  for (int t0 = 0; t0 < NTOK; t0 += 64) {
    int t = t0 + lane;
    int my = -1;
#pragma unroll
    for (int k = 0; k < 4; ++k) if (top_e[t*4+k] == e) my = k;
    unsigned long long m = __ballot(my >= 0);
    if (my >= 0) {
      int pre = __popcll(m & ((1ull << lane) - 1ull));
      pair_tok[base + pre] = t;
      pair_w[base + pre] = top_w[t*4+my];
    }
    base += (int)__popcll(m);
  }
}

// x (f32) -> xb (bf16), once
__global__ __launch_bounds__(256) void k_xbf16(
    const float* __restrict__ x, unsigned short* __restrict__ xb)
{
  int i = (blockIdx.x * 256 + threadIdx.x) * 8;
  f32x4 a = *(const f32x4*)(x + i);
  f32x4 b = *(const f32x4*)(x + i + 4);
  bf16x8 o;
#pragma unroll
  for (int j = 0; j < 4; ++j) { o[j] = (short)f2bf(a[j]); o[4+j] = (short)f2bf(b[j]); }
  *(bf16x8*)(xb + i) = o;
}

// out[t][h] = sum_k w_k * down_b[e_k][h]  (zero-init + down bias)
__global__ __launch_bounds__(256) void k_outinit(
    const int* __restrict__ top_e, const float* __restrict__ top_w,
    const float* __restrict__ db, float* __restrict__ out)
{
  const int t = blockIdx.x;
  const int tid = threadIdx.x;
  const int e0 = top_e[t*4+0], e1 = top_e[t*4+1], e2 = top_e[t*4+2], e3 = top_e[t*4+3];
  const float w0 = top_w[t*4+0], w1 = top_w[t*4+1], w2 = top_w[t*4+2], w3 = top_w[t*4+3];
  const float* b0 = db + (size_t)e0 * HDIM;
  const float* b1 = db + (size_t)e1 * HDIM;
  const float* b2 = db + (size_t)e2 * HDIM;
  const float* b3 = db + (size_t)e3 * HDIM;
  for (int h = tid; h < HDIM; h += 256)
    out[(size_t)t*HDIM + h] = w0*b0[h] + w1*b1[h] + w2*b2[h] + w3*b3[h];
}

// ---------------- gate_up + activation ----------------
// block = MT rows x 128 fc (256 cols, 1KB/row footprint); 4 waves, each wave
// owns 32 fc as two MFMA n-tiles (even fc = lanes' v[0..1], odd fc = v[2..3]).
// Lane B-load = f32x4 (16B granule). A staged via LDS double buffer.
__global__ __launch_bounds__(256, 2) void k_gateup(
    const unsigned short* __restrict__ xb, const float* __restrict__ gw,
    const float* __restrict__ gb, const int* __restrict__ seg,
    const int* __restrict__ pair_tok, const float* __restrict__ pair_w,
    unsigned short* __restrict__ act)
{
  const int e = blockIdx.z;
  const int segs = seg[e];
  const int n_e = seg[e+1] - segs;
  const int m0 = blockIdx.y * MT;
  if (m0 >= n_e) return;
  const int tid = threadIdx.x;
  const int lane = tid & 63;
  const int wid = tid >> 6;
  const int l15 = lane & 15, lg = lane >> 4;
  const int fcb = blockIdx.x * 128 + wid * 32;       // wave fc base
  const int fcE = fcb + 2*l15;                       // even-slot fc (this lane)
  // float column of the f32x4 load, clamped for tail-block validity
  const int colf = min(2*fcb + 4*l15, NGU - 4);

  __shared__ unsigned short Alds[2][MT][40];

  const float* Bq = gw + (size_t)e * HDIM * NGU + colf + (size_t)lg * 8 * NGU;

  // staging: task = row*2 + half16k; thread covers task=tid and task=tid+256
  const unsigned short* sp0 = nullptr;
  const unsigned short* sp1 = nullptr;
  const int r0 = tid >> 1, h0 = tid & 1;
  const int r1 = (tid + 256) >> 1, h1 = tid & 1;
  if (m0 + r0 < n_e) sp0 = xb + (size_t)pair_tok[segs + m0 + r0] * HDIM + h0*16;
  if (tid < 2*MT - 256 && m0 + r1 < n_e)
    sp1 = xb + (size_t)pair_tok[segs + m0 + r1] * HDIM + h1*16;

  f32x4 accgE[MFR], accuE[MFR], accgO[MFR], accuO[MFR];
  {
    f32x4 b = *(const f32x4*)(gb + (size_t)e * NGU + colf);
#pragma unroll
    for (int m = 0; m < MFR; ++m)
#pragma unroll
      for (int r = 0; r < 4; ++r) {
        accgE[m][r] = b[0]; accuE[m][r] = b[1];
        accgO[m][r] = b[2]; accuO[m][r] = b[3];
      }
  }

  auto stage = [&](int ks, int b) {
    bf16x8 z = {0,0,0,0,0,0,0,0};
    bf16x8 v0 = z, v1 = z;
    if (sp0) { v0 = *(const bf16x8*)(sp0 + ks*32); v1 = *(const bf16x8*)(sp0 + ks*32 + 8); }
    *(bf16x8*)&Alds[b][r0][h0*16]     = v0;
    *(bf16x8*)&Alds[b][r0][h0*16 + 8] = v1;
    if (tid < 2*MT - 256) {
      bf16x8 w0 = z, w1 = z;
      if (sp1) { w0 = *(const bf16x8*)(sp1 + ks*32); w1 = *(const bf16x8*)(sp1 + ks*32 + 8); }
      *(bf16x8*)&Alds[b][r1][h1*16]     = w0;
      *(bf16x8*)&Alds[b][r1][h1*16 + 8] = w1;
    }
  };

  f32x4 bA[8];
  auto loadB = [&](int ks) {
    const float* bp = Bq + (size_t)ks * 32 * NGU;
#pragma unroll
    for (int j = 0; j < 8; ++j) bA[j] = *(const f32x4*)(bp + (size_t)j * NGU);
  };

  loadB(0);
  stage(0, 0);
  lds_barrier();
  int buf = 0;

  for (int ks = 0; ks < KSTEPS; ++ks) {
    if (ks + 1 < KSTEPS) stage(ks + 1, buf ^ 1);
    bf16x8 bgE, buE, bgO, buO;
#pragma unroll
    for (int j = 0; j < 8; ++j) {
      bgE[j] = (short)f2bf(bA[j][0]); buE[j] = (short)f2bf(bA[j][1]);
      bgO[j] = (short)f2bf(bA[j][2]); buO[j] = (short)f2bf(bA[j][3]);
    }
    if (ks + 1 < KSTEPS) loadB(ks + 1);
#pragma unroll
    for (int m = 0; m < MFR; ++m) {
      bf16x8 a = *(const bf16x8*)&Alds[buf][m*16 + l15][lg*8];
      accgE[m] = __builtin_amdgcn_mfma_f32_16x16x32_bf16(a, bgE, accgE[m], 0, 0, 0);
      accuE[m] = __builtin_amdgcn_mfma_f32_16x16x32_bf16(a, buE, accuE[m], 0, 0, 0);
      accgO[m] = __builtin_amdgcn_mfma_f32_16x16x32_bf16(a, bgO, accgO[m], 0, 0, 0);
      accuO[m] = __builtin_amdgcn_mfma_f32_16x16x32_bf16(a, buO, accuO[m], 0, 0, 0);
    }
    lds_barrier();
    buf ^= 1;
  }

  // activation epilogue; fold router score; write (even,odd) pair as one dword
  if (fcE < HDIM) {
#pragma unroll
    for (int m = 0; m < MFR; ++m) {
#pragma unroll
      for (int r = 0; r < 4; ++r) {
        int grow = m0 + m*16 + lg*4 + r;
        if (grow < n_e) {
          float pw = pair_w[segs + grow];
          float gE = fminf(accgE[m][r], 7.f);
          float uE = fminf(fmaxf(accuE[m][r], -7.f), 7.f);
          float avE = (uE + 1.f) * (gE / (1.f + __expf(-1.702f * gE))) * pw;
          float gO = fminf(accgO[m][r], 7.f);
          float uO = fminf(fmaxf(accuO[m][r], -7.f), 7.f);
          float avO = (uO + 1.f) * (gO / (1.f + __expf(-1.702f * gO))) * pw;
          unsigned pk = (unsigned)f2bf(avE) | ((unsigned)f2bf(avO) << 16);
          *(unsigned*)&act[(size_t)(segs + grow) * HDIM + fcE] = pk;
        }
      }
    }
  }
}

// ---------------- down projection ----------------
// block = MT rows x 128 cols (512B/row footprint); wave owns 32 cols as two
// n-tiles (even/odd); lane B-load = f32x2 (8B granule).
__global__ __launch_bounds__(256, 3) void k_down(
    const unsigned short* __restrict__ act, const float* __restrict__ dw,
    const int* __restrict__ seg, const int* __restrict__ pair_tok,
    float* __restrict__ out)
{
  const int e = blockIdx.z;
  const int segs = seg[e];
  const int n_e = seg[e+1] - segs;
  const int m0 = blockIdx.y * MT;
  if (m0 >= n_e) return;
  const int tid = threadIdx.x;
  const int lane = tid & 63;
  const int wid = tid >> 6;
  const int l15 = lane & 15, lg = lane >> 4;
  const int cb = blockIdx.x * 128 + wid * 32;
  const int cE = cb + 2*l15;
  const int colc = min(cE, HDIM - 2);

  __shared__ unsigned short Alds[2][MT][40];

  const float* Bq = dw + (size_t)e * HDIM * HDIM + colc + (size_t)lg * 8 * HDIM;

  const unsigned short* sp0 = nullptr;
  const unsigned short* sp1 = nullptr;
  const int r0 = tid >> 1, h0 = tid & 1;
  const int r1 = (tid + 256) >> 1, h1 = tid & 1;
  if (m0 + r0 < n_e) sp0 = act + (size_t)(segs + m0 + r0) * HDIM + h0*16;
  if (tid < 2*MT - 256 && m0 + r1 < n_e)
    sp1 = act + (size_t)(segs + m0 + r1) * HDIM + h1*16;

  f32x4 accE[MFR], accO[MFR];
#pragma unroll
  for (int m = 0; m < MFR; ++m)
#pragma unroll
    for (int r = 0; r < 4; ++r) { accE[m][r] = 0.f; accO[m][r] = 0.f; }

  auto stage = [&](int ks, int b) {
    bf16x8 z = {0,0,0,0,0,0,0,0};
    bf16x8 v0 = z, v1 = z;
    if (sp0) { v0 = *(const bf16x8*)(sp0 + ks*32); v1 = *(const bf16x8*)(sp0 + ks*32 + 8); }
    *(bf16x8*)&Alds[b][r0][h0*16]     = v0;
    *(bf16x8*)&Alds[b][r0][h0*16 + 8] = v1;
    if (tid < 2*MT - 256) {
      bf16x8 w0 = z, w1 = z;
      if (sp1) { w0 = *(const bf16x8*)(sp1 + ks*32); w1 = *(const bf16x8*)(sp1 + ks*32 + 8); }
      *(bf16x8*)&Alds[b][r1][h1*16]     = w0;
      *(bf16x8*)&Alds[b][r1][h1*16 + 8] = w1;
    }
  };

  f32x2 bA[8];
  auto loadB = [&](int ks) {
    const float* bp = Bq + (size_t)ks * 32 * HDIM;
#pragma unroll
    for (int j = 0; j < 8; ++j) bA[j] = *(const f32x2*)(bp + (size_t)j * HDIM);
  };

  loadB(0);
  stage(0, 0);
  lds_barrier();
  int buf = 0;

  for (int ks = 0; ks < KSTEPS; ++ks) {
    if (ks + 1 < KSTEPS) stage(ks + 1, buf ^ 1);
    bf16x8 bfE, bfO;
#pragma unroll
    for (int j = 0; j < 8; ++j) { bfE[j] = (short)f2bf(bA[j][0]); bfO[j] = (short)f2bf(bA[j][1]); }
    if (ks + 1 < KSTEPS) loadB(ks + 1);
#pragma unroll
    for (int m = 0; m < MFR; ++m) {
      bf16x8 a = *(const bf16x8*)&Alds[buf][m*16 + l15][lg*8];
      accE[m] = __builtin_amdgcn_mfma_f32_16x16x32_bf16(a, bfE, accE[m], 0, 0, 0);
      accO[m] = __builtin_amdgcn_mfma_f32_16x16x32_bf16(a, bfO, accO[m], 0, 0, 0);
    }
    lds_barrier();
    buf ^= 1;
  }

  if (cE < HDIM) {
#pragma unroll
    for (int m = 0; m < MFR; ++m) {
#pragma unroll
      for (int r = 0; r < 4; ++r) {
        int grow = m0 + m*16 + lg*4 + r;
        if (grow < n_e) {
          int t = pair_tok[segs + grow];
          atomicAdd(out + (size_t)t * HDIM + cE,     accE[m][r]);
          atomicAdd(out + (size_t)t * HDIM + cE + 1, accO[m][r]);
        }
      }
    }
  }
}

// ---------------- launch ----------------

extern "C" void kernel_launch(void* const* d_in, const int* in_sizes, int n_in,
                              void* d_out, int out_size, void* d_ws, size_t ws_size,
                              hipStream_t stream) {
  const float* x  = (const float*)d_in[0];
  const float* rw = (const float*)d_in[1];
  const float* rb = (const float*)d_in[2];
  const float* gw = (const float*)d_in[3];
  const float* gb = (const float*)d_in[4];
  const float* dw = (const float*)d_in[5];
  const float* db = (const float*)d_in[6];
  float* out = (float*)d_out;

  char* w = (char*)d_ws;
  int*   counts   = (int*)(w);
  int*   seg      = (int*)(w + 64);
  int*   top_e    = (int*)(w + 1024);
  float* top_w    = (float*)(w + 1024 + 8192);
  int*   pair_tok = (int*)(w + 1024 + 16384);
  float* pair_w   = (float*)(w + 1024 + 24576);
  unsigned short* xb  = (unsigned short*)(w + (1 << 20));            // 512 x 2880 bf16
  unsigned short* act = (unsigned short*)(w + (8 << 20));            // 2048 x 2880 bf16

  k_zero<<<1, 64, 0, stream>>>(counts);
  k_router<<<NTOK, 256, 0, stream>>>(x, rw, rb, counts, top_e, top_w);
  k_fill<<<NEXP, 64, 0, stream>>>(top_e, top_w, counts, seg, pair_tok, pair_w);
  k_xbf16<<<(NTOK*HDIM)/(256*8), 256, 0, stream>>>(x, xb);
  k_outinit<<<NTOK, 256, 0, stream>>>(top_e, top_w, db, out);

  dim3 gg(23, 2, NEXP);   // 23 fc tiles (128 fc each) x {main, overflow} x experts
  k_gateup<<<gg, 256, 0, stream>>>(xb, gw, gb, seg, pair_tok, pair_w, act);

  dim3 gd(23, 2, NEXP);   // 23 col tiles (128 cols each) x {main, overflow} x experts
  k_down<<<gd, 256, 0, stream>>>(act, dw, seg, pair_tok, out);
}

// Round 6
// 463.724 us; speedup vs baseline: 1.1937x; 1.0502x over previous
//
#include <hip/hip_runtime.h>
#include <hip/hip_bf16.h>

#define NTOK 512
#define HDIM 2880
#define NGU  5760
#define NEXP 16
#define KSTEPS 90   // 2880 / 32
#define MT 160      // m-tile rows (covers n_e up to 160 in one tile)
#define MFR 10      // MT/16 m-fragments

typedef float  f32x4  __attribute__((ext_vector_type(4)));
typedef float  f32x2  __attribute__((ext_vector_type(2)));
typedef short  bf16x8 __attribute__((ext_vector_type(8)));

__device__ __forceinline__ unsigned short f2bf(float f) {
  union { float f; unsigned u; } a; a.f = f;
  unsigned r = a.u + 0x7FFFu + ((a.u >> 16) & 1u);   // RNE truncate to bf16
  return (unsigned short)(r >> 16);
}

// Barrier that does NOT drain vmcnt: LDS-only wait + raw s_barrier.
// lgkmcnt(0) drains this wave's ds_writes AND ds_reads (RAW+WAR on both LDS
// buffers safe); trailing empty asm = compiler fence (s_barrier is IntrNoMem).
__device__ __forceinline__ void lds_barrier() {
  asm volatile("s_waitcnt lgkmcnt(0)" ::: "memory");
  __builtin_amdgcn_s_barrier();
  asm volatile("" ::: "memory");
}

// ---------------- control kernels ----------------

__global__ void k_zero(int* counts) {
  if (threadIdx.x < NEXP) counts[threadIdx.x] = 0;
}

__global__ __launch_bounds__(256) void k_router(
    const float* __restrict__ x, const float* __restrict__ rw,
    const float* __restrict__ rb, int* __restrict__ counts,
    int* __restrict__ top_e, float* __restrict__ top_w)
{
  const int t = blockIdx.x;
  const int tid = threadIdx.x;
  __shared__ float red[256][17];
  float acc[NEXP];
#pragma unroll
  for (int e = 0; e < NEXP; ++e) acc[e] = 0.f;
  const float* xr = x + (size_t)t * HDIM;
  for (int h = tid; h < HDIM; h += 256) {
    float xv = xr[h];
    const f32x4* wr = (const f32x4*)(rw + (size_t)h * NEXP);
#pragma unroll
    for (int q = 0; q < 4; ++q) {
      f32x4 w = wr[q];
#pragma unroll
      for (int j = 0; j < 4; ++j) acc[q*4+j] += xv * w[j];
    }
  }
#pragma unroll
  for (int e = 0; e < NEXP; ++e) red[tid][e] = acc[e];
  __syncthreads();
  for (int s = 128; s > 0; s >>= 1) {
    if (tid < s) {
#pragma unroll
      for (int e = 0; e < NEXP; ++e) red[tid][e] += red[tid + s][e];
    }
    __syncthreads();
  }
  if (tid == 0) {
    float v[NEXP];
#pragma unroll
    for (int e = 0; e < NEXP; ++e) v[e] = red[0][e] + rb[e];
    int mask = 0; float tv[4]; int ti[4];
    for (int k = 0; k < 4; ++k) {
      float best = -3.4e38f; int bi = 0;
      for (int e = 0; e < NEXP; ++e)
        if (!((mask >> e) & 1) && v[e] > best) { best = v[e]; bi = e; }
      mask |= 1 << bi; tv[k] = best; ti[k] = bi;
    }
    float s = 0.f, ex[4];
    for (int k = 0; k < 4; ++k) { ex[k] = __expf(tv[k] - tv[0]); s += ex[k]; }
    float inv = 1.f / s;
    for (int k = 0; k < 4; ++k) {
      top_e[t*4+k] = ti[k];
      top_w[t*4+k] = ex[k] * inv;
      atomicAdd(&counts[ti[k]], 1);
    }
  }
}

// one wave per expert; deterministic compaction; prefix-scan folded in.
__global__ __launch_bounds__(64) void k_fill(
    const int* __restrict__ top_e, const float* __restrict__ top_w,
    const int* __restrict__ counts, int* __restrict__ seg,
    int* __restrict__ pair_tok, float* __restrict__ pair_w)
{
  const int e = blockIdx.x;
  const int lane = threadIdx.x;
  int base = 0;
  for (int i = 0; i < e; ++i) base += counts[i];
  if (lane == 0) {
    seg[e] = base;
    if (e == NEXP - 1) seg[NEXP] = base + counts[e];
  }
  for (int t0 = 0; t0 < NTOK; t0 += 64) {
    int t = t0 + lane;
    int my = -1;
#pragma unroll
    for (int k = 0; k < 4; ++k) if (top_e[t*4+k] == e) my = k;
    unsigned long long m = __ballot(my >= 0);
    if (my >= 0) {
      int pre = __popcll(m & ((1ull << lane) - 1ull));
      pair_tok[base + pre] = t;
      pair_w[base + pre] = top_w[t*4+my];
    }
    base += (int)__popcll(m);
  }
}

// x (f32) -> xb (bf16), once
__global__ __launch_bounds__(256) void k_xbf16(
    const float* __restrict__ x, unsigned short* __restrict__ xb)
{
  int i = (blockIdx.x * 256 + threadIdx.x) * 8;
  f32x4 a = *(const f32x4*)(x + i);
  f32x4 b = *(const f32x4*)(x + i + 4);
  bf16x8 o;
#pragma unroll
  for (int j = 0; j < 4; ++j) { o[j] = (short)f2bf(a[j]); o[4+j] = (short)f2bf(b[j]); }
  *(bf16x8*)(xb + i) = o;
}

// out[t][h] = sum_k w_k * down_b[e_k][h]  (zero-init + down bias)
__global__ __launch_bounds__(256) void k_outinit(
    const int* __restrict__ top_e, const float* __restrict__ top_w,
    const float* __restrict__ db, float* __restrict__ out)
{
  const int t = blockIdx.x;
  const int tid = threadIdx.x;
  const int e0 = top_e[t*4+0], e1 = top_e[t*4+1], e2 = top_e[t*4+2], e3 = top_e[t*4+3];
  const float w0 = top_w[t*4+0], w1 = top_w[t*4+1], w2 = top_w[t*4+2], w3 = top_w[t*4+3];
  const float* b0 = db + (size_t)e0 * HDIM;
  const float* b1 = db + (size_t)e1 * HDIM;
  const float* b2 = db + (size_t)e2 * HDIM;
  const float* b3 = db + (size_t)e3 * HDIM;
  for (int h = tid; h < HDIM; h += 256)
    out[(size_t)t*HDIM + h] = w0*b0[h] + w1*b1[h] + w2*b2[h] + w3*b3[h];
}

// ---------------- gate_up + activation ----------------
// block = MT rows x 128 fc (256 cols, 1KB/row footprint); 4 waves, each wave
// owns 32 fc as two MFMA n-tiles (even fc, odd fc). Lane B-load = f32x4 NT
// (weights are single-use: nt keeps them from evicting xb/act in L2/L3).
__global__ __launch_bounds__(256, 2) void k_gateup(
    const unsigned short* __restrict__ xb, const float* __restrict__ gw,
    const float* __restrict__ gb, const int* __restrict__ seg,
    const int* __restrict__ pair_tok, const float* __restrict__ pair_w,
    unsigned short* __restrict__ act)
{
  const int e = blockIdx.z;
  const int segs = seg[e];
  const int n_e = seg[e+1] - segs;
  const int m0 = blockIdx.y * MT;
  if (m0 >= n_e) return;
  const int tid = threadIdx.x;
  const int lane = tid & 63;
  const int wid = tid >> 6;
  const int l15 = lane & 15, lg = lane >> 4;
  const int fcb = blockIdx.x * 128 + wid * 32;       // wave fc base
  const int fcE = fcb + 2*l15;                       // even-slot fc (this lane)
  // float column of the f32x4 load, clamped for tail-block validity
  const int colf = min(2*fcb + 4*l15, NGU - 4);

  __shared__ unsigned short Alds[2][MT][40];

  const float* Bq = gw + (size_t)e * HDIM * NGU + colf + (size_t)lg * 8 * NGU;

  // staging: task = row*2 + half16k; thread covers task=tid and task=tid+256
  const unsigned short* sp0 = nullptr;
  const unsigned short* sp1 = nullptr;
  const int r0 = tid >> 1, h0 = tid & 1;
  const int r1 = (tid + 256) >> 1, h1 = tid & 1;
  if (m0 + r0 < n_e) sp0 = xb + (size_t)pair_tok[segs + m0 + r0] * HDIM + h0*16;
  if (tid < 2*MT - 256 && m0 + r1 < n_e)
    sp1 = xb + (size_t)pair_tok[segs + m0 + r1] * HDIM + h1*16;

  f32x4 accgE[MFR], accuE[MFR], accgO[MFR], accuO[MFR];
  {
    f32x4 b = __builtin_nontemporal_load((const f32x4*)(gb + (size_t)e * NGU + colf));
#pragma unroll
    for (int m = 0; m < MFR; ++m)
#pragma unroll
      for (int r = 0; r < 4; ++r) {
        accgE[m][r] = b[0]; accuE[m][r] = b[1];
        accgO[m][r] = b[2]; accuO[m][r] = b[3];
      }
  }

  auto stage = [&](int ks, int b) {
    bf16x8 z = {0,0,0,0,0,0,0,0};
    bf16x8 v0 = z, v1 = z;
    if (sp0) { v0 = *(const bf16x8*)(sp0 + ks*32); v1 = *(const bf16x8*)(sp0 + ks*32 + 8); }
    *(bf16x8*)&Alds[b][r0][h0*16]     = v0;
    *(bf16x8*)&Alds[b][r0][h0*16 + 8] = v1;
    if (tid < 2*MT - 256) {
      bf16x8 w0 = z, w1 = z;
      if (sp1) { w0 = *(const bf16x8*)(sp1 + ks*32); w1 = *(const bf16x8*)(sp1 + ks*32 + 8); }
      *(bf16x8*)&Alds[b][r1][h1*16]     = w0;
      *(bf16x8*)&Alds[b][r1][h1*16 + 8] = w1;
    }
  };

  f32x4 bA[8];
  auto loadB = [&](int ks) {
    const float* bp = Bq + (size_t)ks * 32 * NGU;
#pragma unroll
    for (int j = 0; j < 8; ++j)
      bA[j] = __builtin_nontemporal_load((const f32x4*)(bp + (size_t)j * NGU));
  };

  loadB(0);
  stage(0, 0);
  lds_barrier();
  int buf = 0;

  for (int ks = 0; ks < KSTEPS; ++ks) {
    if (ks + 1 < KSTEPS) stage(ks + 1, buf ^ 1);
    bf16x8 bgE, buE, bgO, buO;
#pragma unroll
    for (int j = 0; j < 8; ++j) {
      bgE[j] = (short)f2bf(bA[j][0]); buE[j] = (short)f2bf(bA[j][1]);
      bgO[j] = (short)f2bf(bA[j][2]); buO[j] = (short)f2bf(bA[j][3]);
    }
    if (ks + 1 < KSTEPS) loadB(ks + 1);
#pragma unroll
    for (int m = 0; m < MFR; ++m) {
      bf16x8 a = *(const bf16x8*)&Alds[buf][m*16 + l15][lg*8];
      accgE[m] = __builtin_amdgcn_mfma_f32_16x16x32_bf16(a, bgE, accgE[m], 0, 0, 0);
      accuE[m] = __builtin_amdgcn_mfma_f32_16x16x32_bf16(a, buE, accuE[m], 0, 0, 0);
      accgO[m] = __builtin_amdgcn_mfma_f32_16x16x32_bf16(a, bgO, accgO[m], 0, 0, 0);
      accuO[m] = __builtin_amdgcn_mfma_f32_16x16x32_bf16(a, buO, accuO[m], 0, 0, 0);
    }
    lds_barrier();
    buf ^= 1;
  }

  // activation epilogue; fold router score; write (even,odd) pair as one dword
  if (fcE < HDIM) {
#pragma unroll
    for (int m = 0; m < MFR; ++m) {
#pragma unroll
      for (int r = 0; r < 4; ++r) {
        int grow = m0 + m*16 + lg*4 + r;
        if (grow < n_e) {
          float pw = pair_w[segs + grow];
          float gE = fminf(accgE[m][r], 7.f);
          float uE = fminf(fmaxf(accuE[m][r], -7.f), 7.f);
          float avE = (uE + 1.f) * (gE / (1.f + __expf(-1.702f * gE))) * pw;
          float gO = fminf(accgO[m][r], 7.f);
          float uO = fminf(fmaxf(accuO[m][r], -7.f), 7.f);
          float avO = (uO + 1.f) * (gO / (1.f + __expf(-1.702f * gO))) * pw;
          unsigned pk = (unsigned)f2bf(avE) | ((unsigned)f2bf(avO) << 16);
          *(unsigned*)&act[(size_t)(segs + grow) * HDIM + fcE] = pk;
        }
      }
    }
  }
}

// ---------------- down projection ----------------
// block = MT rows x 128 cols (512B/row footprint); wave owns 32 cols as two
// n-tiles (even/odd); lane B-load = f32x2 NT (8B granule, 128B/instr/row).
__global__ __launch_bounds__(256, 3) void k_down(
    const unsigned short* __restrict__ act, const float* __restrict__ dw,
    const int* __restrict__ seg, const int* __restrict__ pair_tok,
    float* __restrict__ out)
{
  const int e = blockIdx.z;
  const int segs = seg[e];
  const int n_e = seg[e+1] - segs;
  const int m0 = blockIdx.y * MT;
  if (m0 >= n_e) return;
  const int tid = threadIdx.x;
  const int lane = tid & 63;
  const int wid = tid >> 6;
  const int l15 = lane & 15, lg = lane >> 4;
  const int cb = blockIdx.x * 128 + wid * 32;
  const int cE = cb + 2*l15;
  const int colc = min(cE, HDIM - 2);

  __shared__ unsigned short Alds[2][MT][40];

  const float* Bq = dw + (size_t)e * HDIM * HDIM + colc + (size_t)lg * 8 * HDIM;

  const unsigned short* sp0 = nullptr;
  const unsigned short* sp1 = nullptr;
  const int r0 = tid >> 1, h0 = tid & 1;
  const int r1 = (tid + 256) >> 1, h1 = tid & 1;
  if (m0 + r0 < n_e) sp0 = act + (size_t)(segs + m0 + r0) * HDIM + h0*16;
  if (tid < 2*MT - 256 && m0 + r1 < n_e)
    sp1 = act + (size_t)(segs + m0 + r1) * HDIM + h1*16;

  f32x4 accE[MFR], accO[MFR];
#pragma unroll
  for (int m = 0; m < MFR; ++m)
#pragma unroll
    for (int r = 0; r < 4; ++r) { accE[m][r] = 0.f; accO[m][r] = 0.f; }

  auto stage = [&](int ks, int b) {
    bf16x8 z = {0,0,0,0,0,0,0,0};
    bf16x8 v0 = z, v1 = z;
    if (sp0) { v0 = *(const bf16x8*)(sp0 + ks*32); v1 = *(const bf16x8*)(sp0 + ks*32 + 8); }
    *(bf16x8*)&Alds[b][r0][h0*16]     = v0;
    *(bf16x8*)&Alds[b][r0][h0*16 + 8] = v1;
    if (tid < 2*MT - 256) {
      bf16x8 w0 = z, w1 = z;
      if (sp1) { w0 = *(const bf16x8*)(sp1 + ks*32); w1 = *(const bf16x8*)(sp1 + ks*32 + 8); }
      *(bf16x8*)&Alds[b][r1][h1*16]     = w0;
      *(bf16x8*)&Alds[b][r1][h1*16 + 8] = w1;
    }
  };

  f32x2 bA[8];
  auto loadB = [&](int ks) {
    const float* bp = Bq + (size_t)ks * 32 * HDIM;
#pragma unroll
    for (int j = 0; j < 8; ++j)
      bA[j] = __builtin_nontemporal_load((const f32x2*)(bp + (size_t)j * HDIM));
  };

  loadB(0);
  stage(0, 0);
  lds_barrier();
  int buf = 0;

  for (int ks = 0; ks < KSTEPS; ++ks) {
    if (ks + 1 < KSTEPS) stage(ks + 1, buf ^ 1);
    bf16x8 bfE, bfO;
#pragma unroll
    for (int j = 0; j < 8; ++j) { bfE[j] = (short)f2bf(bA[j][0]); bfO[j] = (short)f2bf(bA[j][1]); }
    if (ks + 1 < KSTEPS) loadB(ks + 1);
#pragma unroll
    for (int m = 0; m < MFR; ++m) {
      bf16x8 a = *(const bf16x8*)&Alds[buf][m*16 + l15][lg*8];
      accE[m] = __builtin_amdgcn_mfma_f32_16x16x32_bf16(a, bfE, accE[m], 0, 0, 0);
      accO[m] = __builtin_amdgcn_mfma_f32_16x16x32_bf16(a, bfO, accO[m], 0, 0, 0);
    }
    lds_barrier();
    buf ^= 1;
  }

  if (cE < HDIM) {
#pragma unroll
    for (int m = 0; m < MFR; ++m) {
#pragma unroll
      for (int r = 0; r < 4; ++r) {
        int grow = m0 + m*16 + lg*4 + r;
        if (grow < n_e) {
          int t = pair_tok[segs + grow];
          atomicAdd(out + (size_t)t * HDIM + cE,     accE[m][r]);
          atomicAdd(out + (size_t)t * HDIM + cE + 1, accO[m][r]);
        }
      }
    }
  }
}

// ---------------- launch ----------------

extern "C" void kernel_launch(void* const* d_in, const int* in_sizes, int n_in,
                              void* d_out, int out_size, void* d_ws, size_t ws_size,
                              hipStream_t stream) {
  const float* x  = (const float*)d_in[0];
  const float* rw = (const float*)d_in[1];
  const float* rb = (const float*)d_in[2];
  const float* gw = (const float*)d_in[3];
  const float* gb = (const float*)d_in[4];
  const float* dw = (const float*)d_in[5];
  const float* db = (const float*)d_in[6];
  float* out = (float*)d_out;

  char* w = (char*)d_ws;
  int*   counts   = (int*)(w);
  int*   seg      = (int*)(w + 64);
  int*   top_e    = (int*)(w + 1024);
  float* top_w    = (float*)(w + 1024 + 8192);
  int*   pair_tok = (int*)(w + 1024 + 16384);
  float* pair_w   = (float*)(w + 1024 + 24576);
  unsigned short* xb  = (unsigned short*)(w + (1 << 20));            // 512 x 2880 bf16
  unsigned short* act = (unsigned short*)(w + (8 << 20));            // 2048 x 2880 bf16

  k_zero<<<1, 64, 0, stream>>>(counts);
  k_router<<<NTOK, 256, 0, stream>>>(x, rw, rb, counts, top_e, top_w);
  k_fill<<<NEXP, 64, 0, stream>>>(top_e, top_w, counts, seg, pair_tok, pair_w);
  k_xbf16<<<(NTOK*HDIM)/(256*8), 256, 0, stream>>>(x, xb);
  k_outinit<<<NTOK, 256, 0, stream>>>(top_e, top_w, db, out);

  dim3 gg(23, 2, NEXP);   // 23 fc tiles (128 fc each) x {main, overflow} x experts
  k_gateup<<<gg, 256, 0, stream>>>(xb, gw, gb, seg, pair_tok, pair_w, act);

  dim3 gd(23, 2, NEXP);   // 23 col tiles (128 cols each) x {main, overflow} x experts
  k_down<<<gd, 256, 0, stream>>>(act, dw, seg, pair_tok, out);
}